// Round 1
// baseline (6122.609 us; speedup 1.0000x reference)
//
#include <hip/hip_runtime.h>
#include <hip/hip_bf16.h>
#include <math.h>

#define BB 8
#define NN 4096
#define KNN 20
#define CH 64
#define SAMPLES (BB*NN*KNN)   /* 655360 */
#define EPSF 1e-5f
#define SLOPE 0.2f

/* ---------------- K1: exact KNN (bit-matched fp32 distances, contract off) ----- */
__global__ __launch_bounds__(64) void knn_kernel(const float* __restrict__ x,
                                                 int* __restrict__ idx_out) {
#pragma clang fp contract(off)
    __shared__ float px[NN], py[NN], pz[NN];      /* 48 KB */
    __shared__ float ld[KNN*64];                  /* 5 KB  */
    __shared__ int   li[KNN*64];                  /* 5 KB  */
    int tid = threadIdx.x;
    int b = blockIdx.x >> 6;                      /* 64 blocks per batch */
    int nbase = (blockIdx.x & 63) << 6;
    const float* xb = x + (size_t)b * 3 * NN;     /* x is (B,3,N) */
    for (int m = tid; m < NN; m += 64) {
        px[m] = xb[m];
        py[m] = xb[NN + m];
        pz[m] = xb[2*NN + m];
    }
#pragma unroll
    for (int j = 0; j < KNN; ++j) ld[j*64 + tid] = __builtin_inff();
    __syncthreads();

    int n = nbase + tid;
    float qx = px[n], qy = py[n], qz = pz[n];
    float sqn = qx*qx; sqn += qy*qy; sqn += qz*qz;   /* same order as ref sum */
    float worst = __builtin_inff();

    for (int m = 0; m < NN; ++m) {
        float mx = px[m], my = py[m], mz = pz[m];
        float inner = qx*mx; inner += qy*my; inner += qz*mz;
        float sqm = mx*mx; sqm += my*my; sqm += mz*mz;
        float d = (sqn - 2.0f*inner) + sqm;          /* ref parenthesization */
        if (d < worst) {                              /* strict: ties keep lower idx */
            int j = KNN - 1;
            while (j > 0) {
                float pd = ld[(j-1)*64 + tid];
                if (pd <= d) break;                   /* equal -> new goes after */
                ld[j*64 + tid] = pd;
                li[j*64 + tid] = li[(j-1)*64 + tid];
                --j;
            }
            ld[j*64 + tid] = d;
            li[j*64 + tid] = m;
            worst = ld[(KNN-1)*64 + tid];
        }
    }
    int* op = idx_out + ((size_t)(b*NN + n)) * KNN;
#pragma unroll
    for (int j = 0; j < KNN; ++j) op[j] = li[j*64 + tid];
}

/* ---------------- K2: per-point projections u,v (edge-conv1 decomposition) ---- */
/* h1[b,n,k,o] = u[b,idx,o] + v[b,n,o]; u = W1[:,0:3]·p, v = (W1[:,3:6]-W1[:,0:3])·p */
__global__ void uv_kernel(const float* __restrict__ x, const float* __restrict__ W1,
                          float* __restrict__ u, float* __restrict__ v) {
    int t = blockIdx.x * 256 + threadIdx.x;       /* t = ((b*N+n)<<6)+o */
    int o = t & 63;
    int n = (t >> 6) & (NN - 1);
    int b = t >> 18;
    float X = x[(b*3 + 0)*NN + n];
    float Y = x[(b*3 + 1)*NN + n];
    float Z = x[(b*3 + 2)*NN + n];
    float w0 = W1[o*6+0], w1 = W1[o*6+1], w2 = W1[o*6+2];
    float w3 = W1[o*6+3], w4 = W1[o*6+4], w5 = W1[o*6+5];
    u[t] = w0*X + w1*Y + w2*Z;
    v[t] = (w3 - w0)*X + (w4 - w1)*Y + (w5 - w2)*Z;
}

/* ---------------- K3: bn1 per-channel sum / sumsq over all (b,n,k) ------------- */
__global__ void stats1_kernel(const int* __restrict__ idxb, const float* __restrict__ u,
                              const float* __restrict__ v, double* __restrict__ stats) {
    int lane = threadIdx.x & 63;                  /* lane = channel */
    int wid  = (blockIdx.x * blockDim.x + threadIdx.x) >> 6;
    int nw   = (gridDim.x * blockDim.x) >> 6;
    double s = 0.0, q = 0.0;
    for (int smp = wid; smp < SAMPLES; smp += nw) {
        int b = smp / (NN*KNN);
        int r = smp - b*(NN*KNN);
        int n = r / KNN;
        int nbr = idxb[smp];
        float h = u[((size_t)(b*NN + nbr) << 6) + lane]
                + v[((size_t)(b*NN + n)   << 6) + lane];
        s += (double)h;
        q += (double)h * (double)h;
    }
    __shared__ double rs[4][64], rq[4][64];
    int w = threadIdx.x >> 6;
    rs[w][lane] = s; rq[w][lane] = q;
    __syncthreads();
    if (threadIdx.x < 64) {
        double ts = rs[0][lane] + rs[1][lane] + rs[2][lane] + rs[3][lane];
        double tq = rq[0][lane] + rq[1][lane] + rq[2][lane] + rq[3][lane];
        atomicAdd(&stats[lane], ts);
        atomicAdd(&stats[64 + lane], tq);
    }
}

/* ---------------- K4/K6: finalize bn -> affine a,b ---------------------------- */
__global__ void fin_kernel(const double* __restrict__ stats, const float* __restrict__ gamma,
                           const float* __restrict__ beta, float* __restrict__ ab) {
    int o = threadIdx.x;
    double cnt = (double)SAMPLES;
    double mean = stats[o] / cnt;
    double var  = stats[64 + o] / cnt - mean*mean;
    float a = (float)((double)gamma[o] / sqrt(var + (double)EPSF));
    ab[o] = a;
    ab[64 + o] = beta[o] - a * (float)mean;
}

/* ---------------- K5: main pass — g=lrelu(bn1(h1)); h2=g·W2ᵀ; stats2 + max_k --- */
/* block = 320 threads = 16 n-points x 20 k. Each thread: one sample, 64-ch h2.   */
__global__ __launch_bounds__(320) void main_kernel(
        const int* __restrict__ idxb, const float* __restrict__ u,
        const float* __restrict__ v, const float* __restrict__ ab1,
        const float* __restrict__ W2, float* __restrict__ maxbuf,
        double* __restrict__ stats2) {
    __shared__ unsigned maxarr[16*65];            /* padded stride 65 vs banks */
    __shared__ float chsum[64], chsq[64];
    int tid = threadIdx.x;
    for (int i = tid; i < 16*65; i += 320) maxarr[i] = 0u;  /* < enc(-inf) */
    if (tid < 64) { chsum[tid] = 0.f; chsq[tid] = 0.f; }
    __syncthreads();

    int ln = tid / 20, k = tid - ln*20;
    int b = blockIdx.x >> 8;                      /* 256 chunks of 16 n per batch */
    int nbase = (blockIdx.x & 255) << 4;
    int n = nbase + ln;
    int smp = (b*NN + n)*KNN + k;
    int nbr = idxb[smp];

    const float4* u4 = (const float4*)(u + ((size_t)(b*NN + nbr) << 6));
    const float4* v4 = (const float4*)(v + ((size_t)(b*NN + n)   << 6));
    const float4* a4 = (const float4*)ab1;
    const float4* b4 = (const float4*)(ab1 + 64);

    float acc[64];
#pragma unroll
    for (int i = 0; i < 64; ++i) acc[i] = 0.f;

#pragma unroll 4
    for (int o4 = 0; o4 < 16; ++o4) {
        float4 uu = u4[o4], vv = v4[o4], aa = a4[o4], bb = b4[o4];
        float g0 = aa.x*(uu.x+vv.x) + bb.x; g0 = g0 >= 0.f ? g0 : SLOPE*g0;
        float g1 = aa.y*(uu.y+vv.y) + bb.y; g1 = g1 >= 0.f ? g1 : SLOPE*g1;
        float g2 = aa.z*(uu.z+vv.z) + bb.z; g2 = g2 >= 0.f ? g2 : SLOPE*g2;
        float g3 = aa.w*(uu.w+vv.w) + bb.w; g3 = g3 >= 0.f ? g3 : SLOPE*g3;
#pragma unroll
        for (int o2 = 0; o2 < 64; ++o2) {
            const float4 w = *(const float4*)(W2 + (o2 << 6) + (o4 << 2)); /* uniform -> s_load */
            acc[o2] += w.x*g0 + w.y*g1 + w.z*g2 + w.w*g3;
        }
    }

    /* max over k via LDS atomic-max on order-preserving uint encoding */
    unsigned basea = ln * 65;
#pragma unroll
    for (int o = 0; o < 64; ++o) {
        unsigned ub = __float_as_uint(acc[o]);
        unsigned e = (ub & 0x80000000u) ? ~ub : (ub | 0x80000000u);
        atomicMax(&maxarr[basea + o], e);
    }

    /* per-channel block sums via wave butterfly (lane o ends holding channel o) */
    int lane = tid & 63;
    float wsum = 0.f, wsq = 0.f;
#pragma unroll
    for (int o = 0; o < 64; ++o) {
        float sv = acc[o];
        float qv = acc[o]*acc[o];
#pragma unroll
        for (int off = 32; off > 0; off >>= 1) {
            sv += __shfl_xor(sv, off);
            qv += __shfl_xor(qv, off);
        }
        if (lane == o) { wsum = sv; wsq = qv; }
    }
    atomicAdd(&chsum[lane], wsum);
    atomicAdd(&chsq[lane],  wsq);
    __syncthreads();

    /* write max (pre-bn2) in (b, o, n) layout for a coalesced epilogue */
    for (int i = tid; i < 16*64; i += 320) {
        int l2 = i >> 6, o = i & 63;
        unsigned e = maxarr[l2*65 + o];
        float mval = (e & 0x80000000u) ? __uint_as_float(e ^ 0x80000000u)
                                       : __uint_as_float(~e);
        maxbuf[(((size_t)b*64 + o) << 12) + (nbase + l2)] = mval;
    }
    if (tid < 64) {
        atomicAdd(&stats2[tid],      (double)chsum[tid]);
        atomicAdd(&stats2[64 + tid], (double)chsq[tid]);
    }
}

/* ---------------- K7: epilogue — bn2 + lrelu on max (monotone, a2>0) ---------- */
__global__ void out_kernel(const float* __restrict__ maxbuf, const float* __restrict__ ab2,
                           float* __restrict__ out) {
    int t = blockIdx.x * 256 + threadIdx.x;       /* (b,o,n) flat — matches out */
    int o = (t >> 12) & 63;
    float h = ab2[o] * maxbuf[t] + ab2[64 + o];
    out[t] = h >= 0.f ? h : SLOPE*h;
}

extern "C" void kernel_launch(void* const* d_in, const int* in_sizes, int n_in,
                              void* d_out, int out_size, void* d_ws, size_t ws_size,
                              hipStream_t stream) {
    const float* x      = (const float*)d_in[0];
    const float* W1     = (const float*)d_in[1];
    const float* gamma1 = (const float*)d_in[2];
    const float* beta1  = (const float*)d_in[3];
    const float* W2     = (const float*)d_in[4];
    const float* gamma2 = (const float*)d_in[5];
    const float* beta2  = (const float*)d_in[6];
    float* out = (float*)d_out;

    char* ws = (char*)d_ws;
    int*    idxb   = (int*)   (ws + 0);           /* 2,621,440 B */
    float*  u      = (float*) (ws + 2621440);     /* 8,388,608 B */
    float*  v      = (float*) (ws + 11010048);    /* 8,388,608 B */
    float*  maxbuf = (float*) (ws + 19398656);    /* 8,388,608 B */
    double* stats1 = (double*)(ws + 27787264);    /* 1 KB */
    double* stats2 = (double*)(ws + 27788288);    /* 1 KB */
    float*  ab1    = (float*) (ws + 27789312);    /* 512 B */
    float*  ab2    = (float*) (ws + 27789824);    /* 512 B */

    hipMemsetAsync(stats1, 0, 2048, stream);      /* zero stats1+stats2 */

    knn_kernel   <<<512, 64, 0, stream>>>(x, idxb);
    uv_kernel    <<<8192, 256, 0, stream>>>(x, W1, u, v);
    stats1_kernel<<<256, 256, 0, stream>>>(idxb, u, v, stats1);
    fin_kernel   <<<1, 64, 0, stream>>>(stats1, gamma1, beta1, ab1);
    main_kernel  <<<2048, 320, 0, stream>>>(idxb, u, v, ab1, W2, maxbuf, stats2);
    fin_kernel   <<<1, 64, 0, stream>>>(stats2, gamma2, beta2, ab2);
    out_kernel   <<<8192, 256, 0, stream>>>(maxbuf, ab2, out);
}

// Round 3
// 432.528 us; speedup vs baseline: 14.1554x; 14.1554x over previous
//
#include <hip/hip_runtime.h>
#include <hip/hip_bf16.h>
#include <math.h>

#define BB 8
#define NN 4096
#define KNN 20
#define CH 64
#define SAMPLES (BB*NN*KNN)   /* 655360 */
#define EPSF 1e-5f
#define SLOPE 0.2f

/* ---- 64-lane bitonic sort on u64 keys (ascending; lane i ends with i-th smallest) */
__device__ __forceinline__ unsigned long long bitonic64(unsigned long long key, int lane) {
#pragma unroll
    for (int k = 2; k <= 64; k <<= 1) {
#pragma unroll
        for (int j = k >> 1; j > 0; j >>= 1) {
            unsigned long long o = __shfl_xor(key, j);
            bool keepMin = (((lane & k) == 0) == ((lane & j) == 0));
            unsigned long long mn = key < o ? key : o;
            unsigned long long mx = key < o ? o : key;
            key = keepMin ? mn : mx;
        }
    }
    return key;
}

/* merge LDS buffer (cnt keys) + incumbent top-20 -> new top-20.
   wbuf[0..127] = overflow buffer; wbuf[128..147] = incumbent mirror.
   NOTE: no cross-lane reads under divergence (ds_bpermute from inactive
   lanes is undefined) — incumbents go through LDS instead. Same-wave DS
   ops are in-order, so write->read needs no barrier. */
__device__ __forceinline__ void flush_buf(volatile unsigned long long* wbuf, int& cnt,
                                          unsigned long long& best, unsigned long long& kth,
                                          int lane) {
    if (lane < KNN) wbuf[128 + lane] = best;
    while (cnt > 0) {
        int take = cnt < 44 ? cnt : 44;
        unsigned long long vv;
        if (lane < take)      vv = wbuf[cnt - take + lane];
        else if (lane >= 44)  vv = wbuf[128 + (lane - 44)];
        else                  vv = ~0ull;
        vv = bitonic64(vv, lane);                 /* full exec here */
        best = vv;
        kth = __shfl(vv, 19);                     /* full exec */
        cnt -= take;
        if (lane < KNN) wbuf[128 + lane] = vv;
    }
}

/* ---------------- K1: exact KNN. One wave per query; wave-shared top-20. ------- */
__global__ __launch_bounds__(512) void knn_kernel(const float* __restrict__ x,
                                                  int* __restrict__ idx_out) {
#pragma clang fp contract(off)
    __shared__ float px[NN], py[NN], pz[NN];                 /* 48 KB */
    __shared__ unsigned long long buf[8][160];               /* 10 KB */
    const int tid = threadIdx.x;
    const int lane = tid & 63;
    const int wv = __builtin_amdgcn_readfirstlane(tid >> 6);
    const int q0 = blockIdx.x * 8;                           /* 8 queries/block */
    const int b = q0 >> 12;
    const float* xb = x + (size_t)b * 3 * NN;
    for (int m = tid; m < NN; m += 512) {
        px[m] = xb[m]; py[m] = xb[NN + m]; pz[m] = xb[2*NN + m];
    }
    __syncthreads();

    const int n = (q0 + wv) & (NN - 1);
    const float qx = px[n], qy = py[n], qz = pz[n];
    float sqn = qx*qx; sqn += qy*qy; sqn += qz*qz;           /* ref summation order */

    unsigned long long best = ~0ull, kth = ~0ull;
    int cnt = 0;

    for (int j = 0; j < 64; ++j) {
        if (cnt > 64) flush_buf(buf[wv], cnt, best, kth, lane);
        const int m = (j << 6) | lane;
        const float mx = px[m], my = py[m], mz = pz[m];
        float inner = qx*mx; inner += qy*my; inner += qz*mz;
        float sqm = mx*mx; sqm += my*my; sqm += mz*mz;
        const float d = (sqn - 2.0f*inner) + sqm;            /* ref parenthesization */
        unsigned uu = __float_as_uint(d);
        unsigned e = uu ^ (((unsigned)((int)uu >> 31)) | 0x80000000u); /* order-preserving */
        unsigned long long key = ((unsigned long long)e << 32) | (unsigned)m;
        if (j == 0) {
            unsigned long long vv = bitonic64(key, lane);
            best = vv;
            kth = __shfl(vv, 19);
        } else {
            bool push = key < kth;
            unsigned long long mask = __ballot(push);
            if (mask) {
                int ofs = (int)__popcll(mask & ((1ull << lane) - 1ull));
                if (push) buf[wv][cnt + ofs] = key;
                cnt += (int)__popcll(mask);
            }
        }
    }
    flush_buf(buf[wv], cnt, best, kth, lane);
    if (lane < KNN)
        idx_out[(size_t)(q0 + wv) * KNN + lane] = (int)(unsigned)(best & 0xFFFFFFFFull);
}

/* ---------------- K2: per-point projections u,v ------------------------------- */
__global__ void uv_kernel(const float* __restrict__ x, const float* __restrict__ W1,
                          float* __restrict__ u, float* __restrict__ v) {
    int t = blockIdx.x * 256 + threadIdx.x;       /* t = ((b*N+n)<<6)+o */
    int o = t & 63;
    int n = (t >> 6) & (NN - 1);
    int b = t >> 18;
    float X = x[(b*3 + 0)*NN + n];
    float Y = x[(b*3 + 1)*NN + n];
    float Z = x[(b*3 + 2)*NN + n];
    float w0 = W1[o*6+0], w1 = W1[o*6+1], w2 = W1[o*6+2];
    float w3 = W1[o*6+3], w4 = W1[o*6+4], w5 = W1[o*6+5];
    u[t] = w0*X + w1*Y + w2*Z;
    v[t] = (w3 - w0)*X + (w4 - w1)*Y + (w5 - w2)*Z;
}

/* ---------------- K3: bn1 sums. lane=channel, wave = 32 points ----------------- */
__global__ __launch_bounds__(256, 4) void stats1_kernel(const int* __restrict__ idxb,
        const float* __restrict__ u, const float* __restrict__ v,
        double* __restrict__ stats) {
    __shared__ float rsum[4][64], rsq[4][64];
    const int tid = threadIdx.x;
    const int lane = tid & 63;
    const int wv = __builtin_amdgcn_readfirstlane(tid >> 6);
    float s = 0.f, q = 0.f;
    const int pt0 = (blockIdx.x * 4 + wv) * 32;   /* 32 points per wave */
    const int b = pt0 >> 12;
    for (int p = 0; p < 32; ++p) {
        const int pt = pt0 + p;
        const float vc = v[((size_t)pt << 6) + lane];
        const int* irow = idxb + (size_t)pt * KNN;
        for (int k = 0; k < KNN; ++k) {
            int nbr = irow[k];
            float h = u[(((size_t)(b << 12) + nbr) << 6) + lane] + vc;
            s += h; q = fmaf(h, h, q);
        }
    }
    rsum[wv][lane] = s; rsq[wv][lane] = q;
    __syncthreads();
    if (tid < 64) {
        float ts = rsum[0][lane]+rsum[1][lane]+rsum[2][lane]+rsum[3][lane];
        float tq = rsq[0][lane]+rsq[1][lane]+rsq[2][lane]+rsq[3][lane];
        atomicAdd(&stats[lane], (double)ts);
        atomicAdd(&stats[64 + lane], (double)tq);
    }
}

/* ---------------- K4/K6: finalize bn -> affine a,b ---------------------------- */
__global__ void fin_kernel(const double* __restrict__ stats, const float* __restrict__ gamma,
                           const float* __restrict__ beta, float* __restrict__ ab) {
    int o = threadIdx.x;
    double cnt = (double)SAMPLES;
    double mean = stats[o] / cnt;
    double var  = stats[64 + o] / cnt - mean*mean;
    float a = (float)((double)gamma[o] / sqrt(var + (double)EPSF));
    ab[o] = a;
    ab[64 + o] = beta[o] - a * (float)mean;
}

/* ---------------- K5: main pass. lane=channel o; W2 row in regs; g via LDS ----- */
__global__ __launch_bounds__(256, 4) void main_kernel(const int* __restrict__ idxb,
        const float* __restrict__ u, const float* __restrict__ v,
        const float* __restrict__ ab1, const float* __restrict__ W2,
        float* __restrict__ maxbuf, double* __restrict__ stats2) {
    __shared__ float w2s[64*65];                  /* padded: conflict-free row reads */
    __shared__ float gbuf[4][64];
    __shared__ float rsum[4][64], rsq[4][64];
    const int tid = threadIdx.x;
    const int lane = tid & 63;
    const int wv = __builtin_amdgcn_readfirstlane(tid >> 6);
    for (int i = tid; i < 4096; i += 256)
        w2s[(i >> 6)*65 + (i & 63)] = W2[i];
    __syncthreads();
    float w[64];
#pragma unroll
    for (int c = 0; c < 64; ++c) w[c] = w2s[lane*65 + c];
    const float a1 = ab1[lane], b1 = ab1[64 + lane];
    float ssum = 0.f, ssq = 0.f;
    const float4* gp = (const float4*)&gbuf[wv][0];

    const int pt0 = (blockIdx.x * 4 + wv) * 8;    /* 8 points per wave */
    const int b = pt0 >> 12;
    for (int p = 0; p < 8; ++p) {
        const int pt = pt0 + p;
        const float vc = v[((size_t)pt << 6) + lane];
        const int* irow = idxb + (size_t)pt * KNN;
        float pmax = -3.4e38f;
        for (int k = 0; k < KNN; ++k) {
            int nbr = irow[k];                    /* uniform -> s_load */
            float uc = u[(((size_t)(b << 12) + nbr) << 6) + lane];
            float g = a1 * (uc + vc) + b1;
            g = fmaxf(g, SLOPE * g);              /* leaky-relu, slope<1 */
            gbuf[wv][lane] = g;
            float h = 0.f;
#pragma unroll
            for (int c4 = 0; c4 < 16; ++c4) {
                float4 g4 = gp[c4];               /* uniform-address broadcast */
                h = fmaf(g4.x, w[c4*4+0], h);
                h = fmaf(g4.y, w[c4*4+1], h);
                h = fmaf(g4.z, w[c4*4+2], h);
                h = fmaf(g4.w, w[c4*4+3], h);
            }
            pmax = fmaxf(pmax, h);
            ssum += h;
            ssq = fmaf(h, h, ssq);
        }
        maxbuf[((size_t)pt << 6) + lane] = pmax;  /* (b,n,o) coalesced */
    }
    rsum[wv][lane] = ssum; rsq[wv][lane] = ssq;
    __syncthreads();
    if (tid < 64) {
        float ts = rsum[0][lane]+rsum[1][lane]+rsum[2][lane]+rsum[3][lane];
        float tq = rsq[0][lane]+rsq[1][lane]+rsq[2][lane]+rsq[3][lane];
        atomicAdd(&stats2[lane], (double)ts);
        atomicAdd(&stats2[64 + lane], (double)tq);
    }
}

/* ---------------- K7: epilogue — transpose (b,n,o)->(b,o,n) + bn2 + lrelu ------ */
__global__ __launch_bounds__(256) void out_kernel(const float* __restrict__ maxbuf,
        const float* __restrict__ ab2, float* __restrict__ out) {
    __shared__ float t[64][65];
    const int tid = threadIdx.x;
    const int b = blockIdx.x >> 6;
    const int n0 = (blockIdx.x & 63) << 6;
#pragma unroll
    for (int i = 0; i < 16; ++i) {
        int r = (tid >> 6) + i*4;                 /* n-row */
        int c = tid & 63;                         /* channel */
        t[r][c] = maxbuf[(((size_t)((b << 12) + n0 + r)) << 6) + c];
    }
    __syncthreads();
#pragma unroll
    for (int i = 0; i < 16; ++i) {
        int o = (tid >> 6) + i*4;
        int nn = tid & 63;
        float a = ab2[o], bb = ab2[64 + o];
        float h = a * t[nn][o] + bb;
        out[(((size_t)(b*64 + o)) << 12) + n0 + nn] = h >= 0.f ? h : SLOPE*h;
    }
}

extern "C" void kernel_launch(void* const* d_in, const int* in_sizes, int n_in,
                              void* d_out, int out_size, void* d_ws, size_t ws_size,
                              hipStream_t stream) {
    const float* x      = (const float*)d_in[0];
    const float* W1     = (const float*)d_in[1];
    const float* gamma1 = (const float*)d_in[2];
    const float* beta1  = (const float*)d_in[3];
    const float* W2     = (const float*)d_in[4];
    const float* gamma2 = (const float*)d_in[5];
    const float* beta2  = (const float*)d_in[6];
    float* out = (float*)d_out;

    char* ws = (char*)d_ws;
    int*    idxb   = (int*)   (ws + 0);           /* 2,621,440 B */
    float*  u      = (float*) (ws + 2621440);     /* 8,388,608 B */
    float*  v      = (float*) (ws + 11010048);    /* 8,388,608 B */
    float*  maxbuf = (float*) (ws + 19398656);    /* 8,388,608 B, layout (b,n,o) */
    double* stats1 = (double*)(ws + 27787264);    /* 1 KB */
    double* stats2 = (double*)(ws + 27788288);    /* 1 KB */
    float*  ab1    = (float*) (ws + 27789312);    /* 512 B */
    float*  ab2    = (float*) (ws + 27789824);    /* 512 B */

    hipMemsetAsync(stats1, 0, 2048, stream);      /* zero stats1+stats2 */

    knn_kernel   <<<4096, 512, 0, stream>>>(x, idxb);
    uv_kernel    <<<8192, 256, 0, stream>>>(x, W1, u, v);
    stats1_kernel<<<256, 256, 0, stream>>>(idxb, u, v, stats1);
    fin_kernel   <<<1, 64, 0, stream>>>(stats1, gamma1, beta1, ab1);
    main_kernel  <<<1024, 256, 0, stream>>>(idxb, u, v, ab1, W2, maxbuf, stats2);
    fin_kernel   <<<1, 64, 0, stream>>>(stats2, gamma2, beta2, ab2);
    out_kernel   <<<512, 256, 0, stream>>>(maxbuf, ab2, out);
}

// Round 4
// 424.130 us; speedup vs baseline: 14.4357x; 1.0198x over previous
//
#include <hip/hip_runtime.h>
#include <hip/hip_bf16.h>
#include <math.h>

#define BB 8
#define NN 4096
#define KNN 20
#define CH 64
#define SAMPLES (BB*NN*KNN)   /* 655360 */
#define EPSF 1e-5f
#define SLOPE 0.2f

/* decode order-preserving uint back to float */
__device__ __forceinline__ float key_decode(unsigned e) {
    return __uint_as_float((e & 0x80000000u) ? (e ^ 0x80000000u) : ~e);
}

/* ---- 64-lane bitonic sort on u64 keys (ascending; lane i ends with i-th smallest) */
__device__ __forceinline__ unsigned long long bitonic64(unsigned long long key, int lane) {
#pragma unroll
    for (int k = 2; k <= 64; k <<= 1) {
#pragma unroll
        for (int j = k >> 1; j > 0; j >>= 1) {
            unsigned long long o = __shfl_xor(key, j);
            bool keepMin = (((lane & k) == 0) == ((lane & j) == 0));
            unsigned long long mn = key < o ? key : o;
            unsigned long long mx = key < o ? o : key;
            key = keepMin ? mn : mx;
        }
    }
    return key;
}

/* merge LDS buffer (cnt keys) + incumbent top-20 -> new top-20.
   wbuf[0..127] = overflow buffer; wbuf[128..147] = incumbent mirror.
   No cross-lane reads under divergence (ds_bpermute from inactive lanes is
   undefined) — incumbents go through LDS. Same-wave DS ops are in-order. */
__device__ __forceinline__ void flush_buf(volatile unsigned long long* wbuf, int& cnt,
                                          unsigned long long& best, float& kthd,
                                          int lane) {
    if (lane < KNN) wbuf[128 + lane] = best;
    while (cnt > 0) {
        int take = cnt < 44 ? cnt : 44;
        unsigned long long vv;
        if (lane < take)      vv = wbuf[cnt - take + lane];
        else if (lane >= 44)  vv = wbuf[128 + (lane - 44)];
        else                  vv = ~0ull;
        vv = bitonic64(vv, lane);                 /* full exec here */
        best = vv;
        unsigned long long kth = __shfl(vv, 19);  /* full exec */
        kthd = key_decode((unsigned)(kth >> 32));
        cnt -= take;
        if (lane < KNN) wbuf[128 + lane] = vv;
    }
}

/* ---------------- K1: exact KNN. One wave per query; wave-shared top-20. ------- */
__global__ __launch_bounds__(512) void knn_kernel(const float* __restrict__ x,
                                                  int* __restrict__ idx_out) {
#pragma clang fp contract(off)
    __shared__ float4 pts[NN];                               /* 64 KB: x,y,z,sq */
    __shared__ unsigned long long buf[8][160];               /* 10 KB */
    const int tid = threadIdx.x;
    const int lane = tid & 63;
    const int wv = __builtin_amdgcn_readfirstlane(tid >> 6);
    const int q0 = blockIdx.x * 8;                           /* 8 queries/block */
    const int b = q0 >> 12;
    const float* xb = x + (size_t)b * 3 * NN;
    for (int m = tid; m < NN; m += 512) {
        float mx = xb[m], my = xb[NN + m], mz = xb[2*NN + m];
        float sq = mx*mx; sq += my*my; sq += mz*mz;          /* ref summation order */
        pts[m] = make_float4(mx, my, mz, sq);
    }
    __syncthreads();

    const int n = (q0 + wv) & (NN - 1);
    const float4 q = pts[n];                                 /* q.w = sqn */

    unsigned long long best = ~0ull;
    float kthd = 0.f;                                        /* set by j==0 sort */
    int cnt = 0;

    for (int j = 0; j < 64; ++j) {
        if (cnt > 64) flush_buf(buf[wv], cnt, best, kthd, lane);
        const int m = (j << 6) | lane;
        const float4 P = pts[m];
        float inner = q.x*P.x; inner += q.y*P.y; inner += q.z*P.z;
        const float d = (q.w - 2.0f*inner) + P.w;            /* bitwise same as R3 */
        if (j == 0) {
            unsigned uu = __float_as_uint(d);
            unsigned e = uu ^ (((unsigned)((int)uu >> 31)) | 0x80000000u);
            unsigned long long key = ((unsigned long long)e << 32) | (unsigned)m;
            unsigned long long vv = bitonic64(key, lane);
            best = vv;
            unsigned long long kth = __shfl(vv, 19);
            kthd = key_decode((unsigned)(kth >> 32));
        } else {
            bool push = d <= kthd;                           /* cheap float test */
            unsigned long long mask = __ballot(push);
            if (mask) {
                if (push) {                                  /* rare: build key here */
                    unsigned uu = __float_as_uint(d);
                    unsigned e = uu ^ (((unsigned)((int)uu >> 31)) | 0x80000000u);
                    unsigned long long key = ((unsigned long long)e << 32) | (unsigned)m;
                    int ofs = (int)__popcll(mask & ((1ull << lane) - 1ull));
                    buf[wv][cnt + ofs] = key;
                }
                cnt += (int)__popcll(mask);
            }
        }
    }
    flush_buf(buf[wv], cnt, best, kthd, lane);
    if (lane < KNN)
        idx_out[(size_t)(q0 + wv) * KNN + lane] = (int)(unsigned)(best & 0xFFFFFFFFull);
}

/* ---------------- K2: per-point projections u,v ------------------------------- */
__global__ void uv_kernel(const float* __restrict__ x, const float* __restrict__ W1,
                          float* __restrict__ u, float* __restrict__ v) {
    int t = blockIdx.x * 256 + threadIdx.x;       /* t = ((b*N+n)<<6)+o */
    int o = t & 63;
    int n = (t >> 6) & (NN - 1);
    int b = t >> 18;
    float X = x[(b*3 + 0)*NN + n];
    float Y = x[(b*3 + 1)*NN + n];
    float Z = x[(b*3 + 2)*NN + n];
    float w0 = W1[o*6+0], w1 = W1[o*6+1], w2 = W1[o*6+2];
    float w3 = W1[o*6+3], w4 = W1[o*6+4], w5 = W1[o*6+5];
    u[t] = w0*X + w1*Y + w2*Z;
    v[t] = (w3 - w0)*X + (w4 - w1)*Y + (w5 - w2)*Z;
}

/* ---------------- K3: bn1 sums. lane=channel, wave = 16 points ----------------- */
__global__ __launch_bounds__(256, 4) void stats1_kernel(const int* __restrict__ idxb,
        const float* __restrict__ u, const float* __restrict__ v,
        double* __restrict__ stats) {
    __shared__ float rsum[4][64], rsq[4][64];
    const int tid = threadIdx.x;
    const int lane = tid & 63;
    const int wv = __builtin_amdgcn_readfirstlane(tid >> 6);
    float s = 0.f, q = 0.f;
    const int pt0 = (blockIdx.x * 4 + wv) * 16;   /* 16 points per wave */
    const int b = pt0 >> 12;
    for (int p = 0; p < 16; ++p) {
        const int pt = pt0 + p;
        const float vc = v[((size_t)pt << 6) + lane];
        const int* irow = idxb + (size_t)pt * KNN;
        for (int k = 0; k < KNN; ++k) {
            int nbr = irow[k];
            float h = u[(((size_t)(b << 12) + nbr) << 6) + lane] + vc;
            s += h; q = fmaf(h, h, q);
        }
    }
    rsum[wv][lane] = s; rsq[wv][lane] = q;
    __syncthreads();
    if (tid < 64) {
        float ts = rsum[0][lane]+rsum[1][lane]+rsum[2][lane]+rsum[3][lane];
        float tq = rsq[0][lane]+rsq[1][lane]+rsq[2][lane]+rsq[3][lane];
        atomicAdd(&stats[lane], (double)ts);
        atomicAdd(&stats[64 + lane], (double)tq);
    }
}

/* ---------------- K4/K6: finalize bn -> affine a,b ---------------------------- */
__global__ void fin_kernel(const double* __restrict__ stats, const float* __restrict__ gamma,
                           const float* __restrict__ beta, float* __restrict__ ab) {
    int o = threadIdx.x;
    double cnt = (double)SAMPLES;
    double mean = stats[o] / cnt;
    double var  = stats[64 + o] / cnt - mean*mean;
    float a = (float)((double)gamma[o] / sqrt(var + (double)EPSF));
    ab[o] = a;
    ab[64 + o] = beta[o] - a * (float)mean;
}

/* ---------------- K5: main pass. lane=channel o; W2 row in regs; g via LDS ----- */
__global__ __launch_bounds__(256, 4) void main_kernel(const int* __restrict__ idxb,
        const float* __restrict__ u, const float* __restrict__ v,
        const float* __restrict__ ab1, const float* __restrict__ W2,
        float* __restrict__ maxbuf, double* __restrict__ stats2) {
    __shared__ float w2s[64*65];                  /* padded: conflict-free row reads */
    __shared__ float gbuf[4][64];
    __shared__ float rsum[4][64], rsq[4][64];
    const int tid = threadIdx.x;
    const int lane = tid & 63;
    const int wv = __builtin_amdgcn_readfirstlane(tid >> 6);
    for (int i = tid; i < 4096; i += 256)
        w2s[(i >> 6)*65 + (i & 63)] = W2[i];
    __syncthreads();
    float w[64];
#pragma unroll
    for (int c = 0; c < 64; ++c) w[c] = w2s[lane*65 + c];
    const float a1 = ab1[lane], b1 = ab1[64 + lane];
    float ssum = 0.f, ssq = 0.f;
    const float4* gp = (const float4*)&gbuf[wv][0];

    const int pt0 = (blockIdx.x * 4 + wv) * 4;    /* 4 points per wave */
    const int b = pt0 >> 12;
    for (int p = 0; p < 4; ++p) {
        const int pt = pt0 + p;
        const float vc = v[((size_t)pt << 6) + lane];
        const int* irow = idxb + (size_t)pt * KNN;
        float pmax = -3.4e38f;
        for (int k = 0; k < KNN; ++k) {
            int nbr = irow[k];                    /* uniform -> s_load */
            float uc = u[(((size_t)(b << 12) + nbr) << 6) + lane];
            float g = a1 * (uc + vc) + b1;
            g = fmaxf(g, SLOPE * g);              /* leaky-relu, slope<1 */
            gbuf[wv][lane] = g;
            float h = 0.f;
#pragma unroll
            for (int c4 = 0; c4 < 16; ++c4) {
                float4 g4 = gp[c4];               /* uniform-address broadcast */
                h = fmaf(g4.x, w[c4*4+0], h);
                h = fmaf(g4.y, w[c4*4+1], h);
                h = fmaf(g4.z, w[c4*4+2], h);
                h = fmaf(g4.w, w[c4*4+3], h);
            }
            pmax = fmaxf(pmax, h);
            ssum += h;
            ssq = fmaf(h, h, ssq);
        }
        maxbuf[((size_t)pt << 6) + lane] = pmax;  /* (b,n,o) coalesced */
    }
    rsum[wv][lane] = ssum; rsq[wv][lane] = ssq;
    __syncthreads();
    if (tid < 64) {
        float ts = rsum[0][lane]+rsum[1][lane]+rsum[2][lane]+rsum[3][lane];
        float tq = rsq[0][lane]+rsq[1][lane]+rsq[2][lane]+rsq[3][lane];
        atomicAdd(&stats2[lane], (double)ts);
        atomicAdd(&stats2[64 + lane], (double)tq);
    }
}

/* ---------------- K7: epilogue — transpose (b,n,o)->(b,o,n) + bn2 + lrelu ------ */
__global__ __launch_bounds__(256) void out_kernel(const float* __restrict__ maxbuf,
        const float* __restrict__ ab2, float* __restrict__ out) {
    __shared__ float t[64][65];
    const int tid = threadIdx.x;
    const int b = blockIdx.x >> 6;
    const int n0 = (blockIdx.x & 63) << 6;
#pragma unroll
    for (int i = 0; i < 16; ++i) {
        int r = (tid >> 6) + i*4;                 /* n-row */
        int c = tid & 63;                         /* channel */
        t[r][c] = maxbuf[(((size_t)((b << 12) + n0 + r)) << 6) + c];
    }
    __syncthreads();
#pragma unroll
    for (int i = 0; i < 16; ++i) {
        int o = (tid >> 6) + i*4;
        int nn = tid & 63;
        float a = ab2[o], bb = ab2[64 + o];
        float h = a * t[nn][o] + bb;
        out[(((size_t)(b*64 + o)) << 12) + n0 + nn] = h >= 0.f ? h : SLOPE*h;
    }
}

extern "C" void kernel_launch(void* const* d_in, const int* in_sizes, int n_in,
                              void* d_out, int out_size, void* d_ws, size_t ws_size,
                              hipStream_t stream) {
    const float* x      = (const float*)d_in[0];
    const float* W1     = (const float*)d_in[1];
    const float* gamma1 = (const float*)d_in[2];
    const float* beta1  = (const float*)d_in[3];
    const float* W2     = (const float*)d_in[4];
    const float* gamma2 = (const float*)d_in[5];
    const float* beta2  = (const float*)d_in[6];
    float* out = (float*)d_out;

    char* ws = (char*)d_ws;
    int*    idxb   = (int*)   (ws + 0);           /* 2,621,440 B */
    float*  u      = (float*) (ws + 2621440);     /* 8,388,608 B */
    float*  v      = (float*) (ws + 11010048);    /* 8,388,608 B */
    float*  maxbuf = (float*) (ws + 19398656);    /* 8,388,608 B, layout (b,n,o) */
    double* stats1 = (double*)(ws + 27787264);    /* 1 KB */
    double* stats2 = (double*)(ws + 27788288);    /* 1 KB */
    float*  ab1    = (float*) (ws + 27789312);    /* 512 B */
    float*  ab2    = (float*) (ws + 27789824);    /* 512 B */

    hipMemsetAsync(stats1, 0, 2048, stream);      /* zero stats1+stats2 */

    knn_kernel   <<<4096, 512, 0, stream>>>(x, idxb);
    uv_kernel    <<<8192, 256, 0, stream>>>(x, W1, u, v);
    stats1_kernel<<<512, 256, 0, stream>>>(idxb, u, v, stats1);
    fin_kernel   <<<1, 64, 0, stream>>>(stats1, gamma1, beta1, ab1);
    main_kernel  <<<2048, 256, 0, stream>>>(idxb, u, v, ab1, W2, maxbuf, stats2);
    fin_kernel   <<<1, 64, 0, stream>>>(stats2, gamma2, beta2, ab2);
    out_kernel   <<<512, 256, 0, stream>>>(maxbuf, ab2, out);
}

// Round 5
// 384.499 us; speedup vs baseline: 15.9236x; 1.1031x over previous
//
#include <hip/hip_runtime.h>
#include <hip/hip_bf16.h>
#include <math.h>

#define BB 8
#define NN 4096
#define KNN 20
#define CH 64
#define SAMPLES (BB*NN*KNN)   /* 655360 */
#define EPSF 1e-5f
#define SLOPE 0.2f

/* decode order-preserving uint back to float */
__device__ __forceinline__ float key_decode(unsigned e) {
    return __uint_as_float((e & 0x80000000u) ? (e ^ 0x80000000u) : ~e);
}

/* rank-select flush: merge ovf[0..cnt) + inc[0..19] -> new exact top-20 in inc.
   Latency-flat: 64 independent broadcast ds_reads (no dependent shuffle chain).
   All LDS deps are same-wave (HW in-order DS); wave_barrier pins compiler order. */
__device__ __forceinline__ void rank_flush(unsigned long long* ovf,
                                           unsigned long long* inc,
                                           unsigned long long* scr,
                                           int& cnt, float& kthd, int lane) {
    while (cnt > 0) {
        int take = cnt < 44 ? cnt : 44;
        unsigned long long key;
        if (lane < take)      key = ovf[cnt - take + lane];
        else if (lane >= 44)  key = inc[lane - 44];
        else                  key = ~0ull;
        scr[lane] = key;
        __builtin_amdgcn_wave_barrier();
        int r = 0;
#pragma unroll
        for (int t = 0; t < 64; ++t) {
            unsigned long long kt = scr[t];       /* uniform addr -> broadcast */
            r += (kt < key) ? 1 : 0;
        }
        __builtin_amdgcn_wave_barrier();
        if (r < KNN) inc[r] = key;                /* padding: r >= take+20 > 19 */
        __builtin_amdgcn_wave_barrier();
        kthd = key_decode((unsigned)(inc[KNN-1] >> 32));
        cnt -= take;
    }
}

/* ---------------- K1: exact KNN. One wave per query; top-20 set via rank-select. */
__global__ __launch_bounds__(512) void knn_kernel(const float* __restrict__ x,
                                                  int* __restrict__ idx_out) {
#pragma clang fp contract(off)
    __shared__ float4 pts[NN];                               /* 64 KB: x,y,z,sq */
    __shared__ unsigned long long wb[8][224];                /* 14 KB/blk        */
    const int tid = threadIdx.x;
    const int lane = tid & 63;
    const int wv = __builtin_amdgcn_readfirstlane(tid >> 6);
    const int q = blockIdx.x * 8 + wv;                       /* one query/wave */
    const int b = q >> 12;
    const int n = q & (NN - 1);
    const float* xb = x + (size_t)b * 3 * NN;
    for (int m = tid; m < NN; m += 512) {
        float mx = xb[m], my = xb[NN + m], mz = xb[2*NN + m];
        float sq = mx*mx; sq += my*my; sq += mz*mz;          /* ref summation order */
        pts[m] = make_float4(mx, my, mz, sq);
    }
    __syncthreads();

    unsigned long long* ovf = &wb[wv][0];                    /* 0..127  overflow  */
    unsigned long long* inc = &wb[wv][128];                  /* 128..147 top-20   */
    unsigned long long* scr = &wb[wv][160];                  /* 160..223 scratch  */

    const float4 Q = pts[n];                                 /* Q.w = sqn */
    float kthd;
    int cnt = 0;

    /* j == 0: rank-select the first 64 candidates directly */
    {
        const float4 P = pts[lane];
        float inner = Q.x*P.x; inner += Q.y*P.y; inner += Q.z*P.z;
        const float d = (Q.w - 2.0f*inner) + P.w;
        unsigned uu = __float_as_uint(d);
        unsigned e = uu ^ (((unsigned)((int)uu >> 31)) | 0x80000000u);
        unsigned long long key = ((unsigned long long)e << 32) | (unsigned)lane;
        scr[lane] = key;
        __builtin_amdgcn_wave_barrier();
        int r = 0;
#pragma unroll
        for (int t = 0; t < 64; ++t) {
            unsigned long long kt = scr[t];
            r += (kt < key) ? 1 : 0;
        }
        __builtin_amdgcn_wave_barrier();
        if (r < KNN) inc[r] = key;
        __builtin_amdgcn_wave_barrier();
        kthd = key_decode((unsigned)(inc[KNN-1] >> 32));
    }

    for (int j = 1; j < 64; ++j) {
        if (cnt > 64) rank_flush(ovf, inc, scr, cnt, kthd, lane);
        const int m = (j << 6) | lane;
        const float4 P = pts[m];
        float inner = Q.x*P.x; inner += Q.y*P.y; inner += Q.z*P.z;
        const float d = (Q.w - 2.0f*inner) + P.w;            /* bitwise same as R4 */
        bool push = d <= kthd;                               /* <=: keep exact ties */
        unsigned long long mask = __ballot(push);
        if (mask) {
            if (push) {
                unsigned uu = __float_as_uint(d);
                unsigned e = uu ^ (((unsigned)((int)uu >> 31)) | 0x80000000u);
                unsigned long long key = ((unsigned long long)e << 32) | (unsigned)m;
                int ofs = (int)__popcll(mask & ((1ull << lane) - 1ull));
                ovf[cnt + ofs] = key;
            }
            cnt += (int)__popcll(mask);
        }
    }
    rank_flush(ovf, inc, scr, cnt, kthd, lane);
    if (lane < KNN)
        idx_out[(size_t)q * KNN + lane] = (int)(unsigned)(inc[lane] & 0xFFFFFFFFull);
}

/* ---------------- K2: per-point projections u,v ------------------------------- */
__global__ void uv_kernel(const float* __restrict__ x, const float* __restrict__ W1,
                          float* __restrict__ u, float* __restrict__ v) {
    int t = blockIdx.x * 256 + threadIdx.x;       /* t = ((b*N+n)<<6)+o */
    int o = t & 63;
    int n = (t >> 6) & (NN - 1);
    int b = t >> 18;
    float X = x[(b*3 + 0)*NN + n];
    float Y = x[(b*3 + 1)*NN + n];
    float Z = x[(b*3 + 2)*NN + n];
    float w0 = W1[o*6+0], w1 = W1[o*6+1], w2 = W1[o*6+2];
    float w3 = W1[o*6+3], w4 = W1[o*6+4], w5 = W1[o*6+5];
    u[t] = w0*X + w1*Y + w2*Z;
    v[t] = (w3 - w0)*X + (w4 - w1)*Y + (w5 - w2)*Z;
}

/* ---------------- K3: bn1 sums. lane=channel, wave = 16 points ----------------- */
__global__ __launch_bounds__(256, 4) void stats1_kernel(const int* __restrict__ idxb,
        const float* __restrict__ u, const float* __restrict__ v,
        double* __restrict__ stats) {
    __shared__ float rsum[4][64], rsq[4][64];
    const int tid = threadIdx.x;
    const int lane = tid & 63;
    const int wv = __builtin_amdgcn_readfirstlane(tid >> 6);
    float s = 0.f, q = 0.f;
    const int pt0 = (blockIdx.x * 4 + wv) * 16;   /* 16 points per wave */
    const int b = pt0 >> 12;
    for (int p = 0; p < 16; ++p) {
        const int pt = pt0 + p;
        const float vc = v[((size_t)pt << 6) + lane];
        const int* irow = idxb + (size_t)pt * KNN;
        for (int k = 0; k < KNN; ++k) {
            int nbr = irow[k];
            float h = u[(((size_t)(b << 12) + nbr) << 6) + lane] + vc;
            s += h; q = fmaf(h, h, q);
        }
    }
    rsum[wv][lane] = s; rsq[wv][lane] = q;
    __syncthreads();
    if (tid < 64) {
        float ts = rsum[0][lane]+rsum[1][lane]+rsum[2][lane]+rsum[3][lane];
        float tq = rsq[0][lane]+rsq[1][lane]+rsq[2][lane]+rsq[3][lane];
        atomicAdd(&stats[lane], (double)ts);
        atomicAdd(&stats[64 + lane], (double)tq);
    }
}

/* ---------------- K4/K6: finalize bn -> affine a,b ---------------------------- */
__global__ void fin_kernel(const double* __restrict__ stats, const float* __restrict__ gamma,
                           const float* __restrict__ beta, float* __restrict__ ab) {
    int o = threadIdx.x;
    double cnt = (double)SAMPLES;
    double mean = stats[o] / cnt;
    double var  = stats[64 + o] / cnt - mean*mean;
    float a = (float)((double)gamma[o] / sqrt(var + (double)EPSF));
    ab[o] = a;
    ab[64 + o] = beta[o] - a * (float)mean;
}

/* ---------------- K5: main pass. lane=channel o; W2 row in regs; g via LDS ----- */
__global__ __launch_bounds__(256, 4) void main_kernel(const int* __restrict__ idxb,
        const float* __restrict__ u, const float* __restrict__ v,
        const float* __restrict__ ab1, const float* __restrict__ W2,
        float* __restrict__ maxbuf, double* __restrict__ stats2) {
    __shared__ float w2s[64*65];                  /* padded: conflict-free row reads */
    __shared__ float gbuf[4][64];
    __shared__ float rsum[4][64], rsq[4][64];
    const int tid = threadIdx.x;
    const int lane = tid & 63;
    const int wv = __builtin_amdgcn_readfirstlane(tid >> 6);
    for (int i = tid; i < 4096; i += 256)
        w2s[(i >> 6)*65 + (i & 63)] = W2[i];
    __syncthreads();
    float w[64];
#pragma unroll
    for (int c = 0; c < 64; ++c) w[c] = w2s[lane*65 + c];
    const float a1 = ab1[lane], b1 = ab1[64 + lane];
    float ssum = 0.f, ssq = 0.f;
    const float4* gp = (const float4*)&gbuf[wv][0];

    const int pt0 = (blockIdx.x * 4 + wv) * 4;    /* 4 points per wave */
    const int b = pt0 >> 12;
    for (int p = 0; p < 4; ++p) {
        const int pt = pt0 + p;
        const float vc = v[((size_t)pt << 6) + lane];
        const int* irow = idxb + (size_t)pt * KNN;
        float pmax = -3.4e38f;
        for (int k = 0; k < KNN; ++k) {
            int nbr = irow[k];                    /* uniform -> s_load */
            float uc = u[(((size_t)(b << 12) + nbr) << 6) + lane];
            float g = a1 * (uc + vc) + b1;
            g = fmaxf(g, SLOPE * g);              /* leaky-relu, slope<1 */
            gbuf[wv][lane] = g;
            float h = 0.f;
#pragma unroll
            for (int c4 = 0; c4 < 16; ++c4) {
                float4 g4 = gp[c4];               /* uniform-address broadcast */
                h = fmaf(g4.x, w[c4*4+0], h);
                h = fmaf(g4.y, w[c4*4+1], h);
                h = fmaf(g4.z, w[c4*4+2], h);
                h = fmaf(g4.w, w[c4*4+3], h);
            }
            pmax = fmaxf(pmax, h);
            ssum += h;
            ssq = fmaf(h, h, ssq);
        }
        maxbuf[((size_t)pt << 6) + lane] = pmax;  /* (b,n,o) coalesced */
    }
    rsum[wv][lane] = ssum; rsq[wv][lane] = ssq;
    __syncthreads();
    if (tid < 64) {
        float ts = rsum[0][lane]+rsum[1][lane]+rsum[2][lane]+rsum[3][lane];
        float tq = rsq[0][lane]+rsq[1][lane]+rsq[2][lane]+rsq[3][lane];
        atomicAdd(&stats2[lane], (double)ts);
        atomicAdd(&stats2[64 + lane], (double)tq);
    }
}

/* ---------------- K7: epilogue — transpose (b,n,o)->(b,o,n) + bn2 + lrelu ------ */
__global__ __launch_bounds__(256) void out_kernel(const float* __restrict__ maxbuf,
        const float* __restrict__ ab2, float* __restrict__ out) {
    __shared__ float t[64][65];
    const int tid = threadIdx.x;
    const int b = blockIdx.x >> 6;
    const int n0 = (blockIdx.x & 63) << 6;
#pragma unroll
    for (int i = 0; i < 16; ++i) {
        int r = (tid >> 6) + i*4;                 /* n-row */
        int c = tid & 63;                         /* channel */
        t[r][c] = maxbuf[(((size_t)((b << 12) + n0 + r)) << 6) + c];
    }
    __syncthreads();
#pragma unroll
    for (int i = 0; i < 16; ++i) {
        int o = (tid >> 6) + i*4;
        int nn = tid & 63;
        float a = ab2[o], bb = ab2[64 + o];
        float h = a * t[nn][o] + bb;
        out[(((size_t)(b*64 + o)) << 12) + n0 + nn] = h >= 0.f ? h : SLOPE*h;
    }
}

extern "C" void kernel_launch(void* const* d_in, const int* in_sizes, int n_in,
                              void* d_out, int out_size, void* d_ws, size_t ws_size,
                              hipStream_t stream) {
    const float* x      = (const float*)d_in[0];
    const float* W1     = (const float*)d_in[1];
    const float* gamma1 = (const float*)d_in[2];
    const float* beta1  = (const float*)d_in[3];
    const float* W2     = (const float*)d_in[4];
    const float* gamma2 = (const float*)d_in[5];
    const float* beta2  = (const float*)d_in[6];
    float* out = (float*)d_out;

    char* ws = (char*)d_ws;
    int*    idxb   = (int*)   (ws + 0);           /* 2,621,440 B */
    float*  u      = (float*) (ws + 2621440);     /* 8,388,608 B */
    float*  v      = (float*) (ws + 11010048);    /* 8,388,608 B */
    float*  maxbuf = (float*) (ws + 19398656);    /* 8,388,608 B, layout (b,n,o) */
    double* stats1 = (double*)(ws + 27787264);    /* 1 KB */
    double* stats2 = (double*)(ws + 27788288);    /* 1 KB */
    float*  ab1    = (float*) (ws + 27789312);    /* 512 B */
    float*  ab2    = (float*) (ws + 27789824);    /* 512 B */

    hipMemsetAsync(stats1, 0, 2048, stream);      /* zero stats1+stats2 */

    knn_kernel   <<<4096, 512, 0, stream>>>(x, idxb);
    uv_kernel    <<<8192, 256, 0, stream>>>(x, W1, u, v);
    stats1_kernel<<<512, 256, 0, stream>>>(idxb, u, v, stats1);
    fin_kernel   <<<1, 64, 0, stream>>>(stats1, gamma1, beta1, ab1);
    main_kernel  <<<2048, 256, 0, stream>>>(idxb, u, v, ab1, W2, maxbuf, stats2);
    fin_kernel   <<<1, 64, 0, stream>>>(stats2, gamma2, beta2, ab2);
    out_kernel   <<<512, 256, 0, stream>>>(maxbuf, ab2, out);
}